// Round 6
// baseline (870.548 us; speedup 1.0000x reference)
//
#include <hip/hip_runtime.h>
#include <stdint.h>

#define NN   8192
#define DIN  512
#define DOUT 512
#define ALPHA 0.2f

typedef float          floatx4  __attribute__((ext_vector_type(4)));
typedef short          shortx8  __attribute__((ext_vector_type(8)));
typedef unsigned short ushortx4 __attribute__((ext_vector_type(4)));
typedef int            intx4    __attribute__((ext_vector_type(4)));

__device__ inline unsigned short f2bf(float x) {
    union { float f; unsigned u; } v; v.f = x;
    return (unsigned short)((v.u + 0x7FFFu + ((v.u >> 16) & 1u)) >> 16);
}
__device__ inline unsigned encf(float x) {
    union { float f; unsigned u; } v; v.f = x;
    return (v.u & 0x80000000u) ? ~v.u : (v.u | 0x80000000u);
}
__device__ inline float decf(unsigned e) {
    union { float f; unsigned u; } v;
    v.u = (e & 0x80000000u) ? (e & 0x7FFFFFFFu) : ~e;
    return v.f;
}
__device__ inline float lrelu(float x) { return fmaxf(x, ALPHA * x); }

// ---------------------------------------------------------------------------
// Kernel T: WT[n][k] = bf16(W[k][n])   (512x512)
// ---------------------------------------------------------------------------
__global__ __launch_bounds__(256) void transpose_w(const float* __restrict__ W,
                                                   unsigned short* __restrict__ WT) {
    __shared__ float tile[32][33];
    const int t = threadIdx.x;
    const int x = t & 31, y = t >> 5;
    const int tr = (blockIdx.x >> 4) * 32, tc = (blockIdx.x & 15) * 32;
#pragma unroll
    for (int i = 0; i < 4; i++) {
        int r = y + i * 8;
        tile[r][x] = W[(size_t)(tr + r) * DOUT + tc + x];
    }
    __syncthreads();
#pragma unroll
    for (int i = 0; i < 4; i++) {
        int r = y + i * 8;
        WT[(size_t)(tc + r) * DIN + tr + x] = f2bf(tile[x][r]);
    }
}

// ---------------------------------------------------------------------------
// Kernel A: Wh = h @ W (bf16 MFMA). 512 blocks x 16 rows, 4 waves (16r x 128c).
// 2-stage register pipeline. Writes WhT (bf16, col-major), f1, f2, max(f2).
// ---------------------------------------------------------------------------
__global__ __launch_bounds__(256) void gemm_wh(
    const float* __restrict__ h, const unsigned short* __restrict__ WT,
    const float* __restrict__ a, unsigned short* __restrict__ WhT,
    float* __restrict__ f1, float* __restrict__ f2, unsigned* __restrict__ Menc)
{
    __shared__ float f1s[4][16], f2s[4][16];
    const int t = threadIdx.x;
    const int w = t >> 6, lane = t & 63, l15 = lane & 15, q = lane >> 4;
    const int r0 = blockIdx.x * 16;
    const int wc0 = w * 128;

    floatx4 acc[8];
    const floatx4 z4 = {0.f, 0.f, 0.f, 0.f};
#pragma unroll
    for (int j = 0; j < 8; j++) acc[j] = z4;

    const float* hp = &h[(size_t)(r0 + l15) * DIN + q * 8];
    const unsigned short* bp = &WT[(size_t)(wc0 + l15) * DIN + q * 8];

    floatx4 hA[2][2];
    shortx8 bB[2][8];
    hA[0][0] = *(const floatx4*)hp;
    hA[0][1] = *(const floatx4*)(hp + 4);
#pragma unroll
    for (int nt = 0; nt < 8; nt++)
        bB[0][nt] = *(const shortx8*)(bp + (size_t)nt * 16 * DIN);

#pragma unroll 2
    for (int it = 0; it < 16; ++it) {
        const int c = it & 1, n = c ^ 1;
        const int kn = ((it + 1) & 15) * 32;
        hA[n][0] = *(const floatx4*)(hp + kn);
        hA[n][1] = *(const floatx4*)(hp + kn + 4);
#pragma unroll
        for (int nt = 0; nt < 8; nt++)
            bB[n][nt] = *(const shortx8*)(bp + (size_t)nt * 16 * DIN + kn);

        shortx8 af;
#pragma unroll
        for (int j = 0; j < 8; j++)
            af[j] = (short)f2bf(hA[c][j >> 2][j & 3]);
#pragma unroll
        for (int nt = 0; nt < 8; nt++)
            acc[nt] = __builtin_amdgcn_mfma_f32_16x16x32_bf16(af, bB[c][nt], acc[nt], 0, 0, 0);
    }

    // epilogue
    float a1v[8], a2v[8];
#pragma unroll
    for (int nt = 0; nt < 8; nt++) {
        int col = wc0 + nt * 16 + l15;
        a1v[nt] = a[col];
        a2v[nt] = a[DOUT + col];
    }
#pragma unroll
    for (int nt = 0; nt < 8; nt++) {
        int col = wc0 + nt * 16 + l15;
        ushortx4 pk;
#pragma unroll
        for (int reg = 0; reg < 4; reg++) pk[reg] = f2bf(acc[nt][reg]);
        *(ushortx4*)&WhT[(size_t)col * NN + r0 + q * 4] = pk;
    }
    float s1a[4], s2a[4];
#pragma unroll
    for (int reg = 0; reg < 4; reg++) {
        float s1 = 0.f, s2 = 0.f;
#pragma unroll
        for (int nt = 0; nt < 8; nt++) {
            s1 += acc[nt][reg] * a1v[nt];
            s2 += acc[nt][reg] * a2v[nt];
        }
        s1 += __shfl_xor(s1, 1, 64); s2 += __shfl_xor(s2, 1, 64);
        s1 += __shfl_xor(s1, 2, 64); s2 += __shfl_xor(s2, 2, 64);
        s1 += __shfl_xor(s1, 4, 64); s2 += __shfl_xor(s2, 4, 64);
        s1 += __shfl_xor(s1, 8, 64); s2 += __shfl_xor(s2, 8, 64);
        s1a[reg] = s1; s2a[reg] = s2;
    }
    if (l15 == 0) {
#pragma unroll
        for (int reg = 0; reg < 4; reg++) {
            f1s[w][q * 4 + reg] = s1a[reg];
            f2s[w][q * 4 + reg] = s2a[reg];
        }
    }
    __syncthreads();
    if (t < 16) {
        float v1 = f1s[0][t] + f1s[1][t] + f1s[2][t] + f1s[3][t];
        float v2 = f2s[0][t] + f2s[1][t] + f2s[2][t] + f2s[3][t];
        f1[r0 + t] = v1;
        f2[r0 + t] = v2;
        float mx = v2;
        mx = fmaxf(mx, __shfl_xor(mx, 1, 64));
        mx = fmaxf(mx, __shfl_xor(mx, 2, 64));
        mx = fmaxf(mx, __shfl_xor(mx, 4, 64));
        mx = fmaxf(mx, __shfl_xor(mx, 8, 64));
        if (t == 0) atomicMax(Menc, encf(mx));
    }
}

// ---------------------------------------------------------------------------
// Kernel 2: GAT aggregation partials. Grid = 1024 blocks = 256 row-blocks x
// 4 k-quarters. XCD-BOUND K-SPLIT: kq = (blockIdx&7)>>1, so (assuming the
// usual round-robin blockIdx%8 -> XCD dispatch) each XCD reads ONE 2 MB slice
// of WhT (512 cols x 2048 k x bf16) that fits its 4 MB L2 -> B-fragments hit
// L2 instead of saturating the ~5 TB/s Infinity-fabric path (the R2/R4
// invariant: ~2.1 wave-iters/us/CU regardless of occupancy). adj is streamed
// with NONTEMPORAL loads so its 268 MB doesn't thrash the B working set.
// rb is rotated by kq*64 so the 4 atomic writers of a row-block stay
// temporally separated. Inner loop unchanged from R2/R4 (proven).
// ---------------------------------------------------------------------------
__global__ __launch_bounds__(256, 4) void gat_agg_part(
    const int* __restrict__ adj, const unsigned short* __restrict__ WhT,
    const float* __restrict__ f1, const float* __restrict__ f2,
    const unsigned* __restrict__ Menc, float* __restrict__ outacc,
    float* __restrict__ lsum)
{
    const int t = threadIdx.x;
    const int cw = t >> 6, lane = t & 63, l15 = lane & 15, q = lane >> 4;
    const int b = blockIdx.x;
    const int low3 = b & 7;
    const int kq = low3 >> 1;                       // XCD-pair -> k-quarter
    const int sub = low3 & 1;
    const int j8 = b >> 3;                          // 0..127
    const int rb = (j8 + sub * 128 + kq * 64) & 255;
    const int r0 = rb * 32;
    const int wc0 = cw * 128;
    const int kbase = kq * 2048;

    const float M = decf(*Menc);
    const float f1v0 = f1[r0 + l15];
    const float f1v1 = f1[r0 + 16 + l15];
    const float mi0 = lrelu(f1v0 + M);
    const float mi1 = lrelu(f1v1 + M);

    floatx4 acc[2][8];
    const floatx4 z4 = {0.f, 0.f, 0.f, 0.f};
#pragma unroll
    for (int i = 0; i < 2; i++)
#pragma unroll
        for (int j = 0; j < 8; j++) acc[i][j] = z4;
    float ls0 = 0.f, ls1 = 0.f;

    const int* ap0 = adj + (size_t)(r0 + l15) * NN + kbase + q * 8;
    const int* ap1 = ap0 + (size_t)16 * NN;
    const unsigned short* bp = WhT + (size_t)(wc0 + l15) * NN + kbase + q * 8;
    const float* fp = f2 + kbase + q * 8;

    intx4   adjA[2][4];
    shortx8 bfr[2][8];
    floatx4 f2f[2][2];

    adjA[0][0] = __builtin_nontemporal_load((const intx4*)(ap0));
    adjA[0][1] = __builtin_nontemporal_load((const intx4*)(ap0 + 4));
    adjA[0][2] = __builtin_nontemporal_load((const intx4*)(ap1));
    adjA[0][3] = __builtin_nontemporal_load((const intx4*)(ap1 + 4));
#pragma unroll
    for (int nt = 0; nt < 8; nt++)
        bfr[0][nt] = *(const shortx8*)(bp + (size_t)nt * 16 * NN);
    f2f[0][0] = *(const floatx4*)fp;
    f2f[0][1] = *(const floatx4*)(fp + 4);

#pragma unroll 2
    for (int it = 0; it < 64; ++it) {
        const int c = it & 1, n = c ^ 1;
        const int kn = ((it + 1) & 63) * 32;   // wraps to 0 on last iter (harmless)

        adjA[n][0] = __builtin_nontemporal_load((const intx4*)(ap0 + kn));
        adjA[n][1] = __builtin_nontemporal_load((const intx4*)(ap0 + kn + 4));
        adjA[n][2] = __builtin_nontemporal_load((const intx4*)(ap1 + kn));
        adjA[n][3] = __builtin_nontemporal_load((const intx4*)(ap1 + kn + 4));
#pragma unroll
        for (int nt = 0; nt < 8; nt++)
            bfr[n][nt] = *(const shortx8*)(bp + (size_t)nt * 16 * NN + kn);
        f2f[n][0] = *(const floatx4*)(fp + kn);
        f2f[n][1] = *(const floatx4*)(fp + kn + 4);

        // p fragments, directly in MFMA A-operand layout (m=l15, k=q*8+j)
        unsigned pb0[8], pb1[8];
#pragma unroll
        for (int j = 0; j < 8; j++) {
            const float fj = f2f[c][j >> 2][j & 3];
            const int a0 = (j < 4) ? adjA[c][0][j & 3] : adjA[c][1][j & 3];
            const int a1 = (j < 4) ? adjA[c][2][j & 3] : adjA[c][3][j & 3];
            float p0 = __expf(lrelu(f1v0 + fj) - mi0);
            p0 = a0 ? p0 : 0.f;
            ls0 += p0;
            pb0[j] = __float_as_uint(p0);
            float p1 = __expf(lrelu(f1v1 + fj) - mi1);
            p1 = a1 ? p1 : 0.f;
            ls1 += p1;
            pb1[j] = __float_as_uint(p1);
        }
        union { unsigned u[4]; shortx8 v; } u0, u1;
#pragma unroll
        for (int j = 0; j < 4; j++) {
            u0.u[j] = __builtin_amdgcn_perm(pb0[2 * j + 1], pb0[2 * j], 0x07060302u);
            u1.u[j] = __builtin_amdgcn_perm(pb1[2 * j + 1], pb1[2 * j], 0x07060302u);
        }
        const shortx8 af0 = u0.v, af1 = u1.v;

#pragma unroll
        for (int nt = 0; nt < 8; nt++) {
            acc[0][nt] = __builtin_amdgcn_mfma_f32_16x16x32_bf16(af0, bfr[c][nt], acc[0][nt], 0, 0, 0);
            acc[1][nt] = __builtin_amdgcn_mfma_f32_16x16x32_bf16(af1, bfr[c][nt], acc[1][nt], 0, 0, 0);
        }
    }

    // row sums for this k-quarter (combine q-lanes; every lane gets full sum)
    ls0 += __shfl_xor(ls0, 16, 64); ls0 += __shfl_xor(ls0, 32, 64);
    ls1 += __shfl_xor(ls1, 16, 64); ls1 += __shfl_xor(ls1, 32, 64);
    if (cw == 0 && lane < 16) {
        atomicAdd(&lsum[r0 + lane], ls0);
        atomicAdd(&lsum[r0 + 16 + lane], ls1);
    }

    // merge partial O-tile into global accumulator (C-layout: row=q*4+reg)
#pragma unroll
    for (int mt = 0; mt < 2; mt++) {
#pragma unroll
        for (int nt = 0; nt < 8; nt++) {
            const int col = wc0 + nt * 16 + l15;
#pragma unroll
            for (int reg = 0; reg < 4; reg++) {
                const int row = mt * 16 + q * 4 + reg;
                atomicAdd(&outacc[(size_t)(r0 + row) * DOUT + col], acc[mt][nt][reg]);
            }
        }
    }
}

// ---------------------------------------------------------------------------
// Kernel 3: out = elu(acc / lsum), in place. 4096 blocks x 256 threads,
// each block 2 rows, float4 per thread.
// ---------------------------------------------------------------------------
__global__ __launch_bounds__(256) void finalize(
    float* __restrict__ out, const float* __restrict__ lsum)
{
    const int t = threadIdx.x;
    const int row = blockIdx.x * 2 + (t >> 7);
    const int c4 = (t & 127) * 4;
    const float iv = 1.f / lsum[row];
    float* p = &out[(size_t)row * DOUT + c4];
    floatx4 v = *(const floatx4*)p;
    floatx4 o;
#pragma unroll
    for (int j = 0; j < 4; j++) {
        const float x = v[j] * iv;
        o[j] = (x > 0.f) ? x : (__expf(x) - 1.f);
    }
    *(floatx4*)p = o;
}

// ---------------------------------------------------------------------------
extern "C" void kernel_launch(void* const* d_in, const int* in_sizes, int n_in,
                              void* d_out, int out_size, void* d_ws, size_t ws_size,
                              hipStream_t stream) {
    const float* h   = (const float*)d_in[0];
    const int*   adj = (const int*)d_in[1];
    const float* W   = (const float*)d_in[2];
    const float* a   = (const float*)d_in[3];
    float* out = (float*)d_out;

    char* ws = (char*)d_ws;
    unsigned short* WT   = (unsigned short*)ws;                        // 512 KB
    unsigned short* WhT  = (unsigned short*)(ws + 524288);             // 8 MB
    float*          f1   = (float*)(ws + 524288 + 8388608);            // 32 KB
    float*          f2   = (float*)(ws + 524288 + 8388608 + 32768);    // 32 KB
    float*          lsum = (float*)(ws + 524288 + 8388608 + 65536);    // 32 KB
    unsigned*       Menc = (unsigned*)(ws + 524288 + 8388608 + 98304); // 4 B

    hipMemsetAsync(out, 0, (size_t)NN * DOUT * sizeof(float), stream);
    hipMemsetAsync(lsum, 0, NN * sizeof(float), stream);
    hipMemsetAsync(Menc, 0, 4, stream);
    transpose_w<<<256, 256, 0, stream>>>(W, WT);
    gemm_wh<<<512, 256, 0, stream>>>(h, WT, a, WhT, f1, f2, Menc);
    gat_agg_part<<<1024, 256, 0, stream>>>(adj, WhT, f1, f2, Menc, out, lsum);
    finalize<<<4096, 256, 0, stream>>>(out, lsum);
}

// Round 8
// 718.499 us; speedup vs baseline: 1.2116x; 1.2116x over previous
//
#include <hip/hip_runtime.h>
#include <stdint.h>

#define NN   8192
#define DIN  512
#define DOUT 512
#define ALPHA 0.2f

typedef float          floatx4  __attribute__((ext_vector_type(4)));
typedef short          shortx8  __attribute__((ext_vector_type(8)));
typedef unsigned short ushortx4 __attribute__((ext_vector_type(4)));
typedef int            intx4    __attribute__((ext_vector_type(4)));

__device__ inline unsigned short f2bf(float x) {
    union { float f; unsigned u; } v; v.f = x;
    return (unsigned short)((v.u + 0x7FFFu + ((v.u >> 16) & 1u)) >> 16);
}
__device__ inline unsigned encf(float x) {
    union { float f; unsigned u; } v; v.f = x;
    return (v.u & 0x80000000u) ? ~v.u : (v.u | 0x80000000u);
}
__device__ inline float decf(unsigned e) {
    union { float f; unsigned u; } v;
    v.u = (e & 0x80000000u) ? (e & 0x7FFFFFFFu) : ~e;
    return v.f;
}
__device__ inline float lrelu(float x) { return fmaxf(x, ALPHA * x); }

// ---------------------------------------------------------------------------
// Kernel P: pack adj into bitmask, k-transposed: bits[kt][row], kt = k>>5.
// Block = one row, 256 threads, 32 iters of coalesced 1 KB reads; ballot
// packs 64 lanes -> u64 -> two u32 stores. adj read ONCE (nt: keep L3 clean).
// ---------------------------------------------------------------------------
__global__ __launch_bounds__(256) void pack_adj(const int* __restrict__ adj,
                                                unsigned* __restrict__ bits) {
    const int row = blockIdx.x;
    const int t = threadIdx.x;
    const int w = t >> 6, lane = t & 63;
    const int* rp = adj + (size_t)row * NN;
#pragma unroll 4
    for (int it = 0; it < 32; ++it) {
        const int col = it * 256 + w * 64 + lane;
        const int v = __builtin_nontemporal_load(rp + col);
        const unsigned long long m = __ballot(v > 0);
        if (lane == 0) {
            const int kt = it * 8 + w * 2;
            bits[(size_t)kt * NN + row] = (unsigned)m;
            bits[(size_t)(kt + 1) * NN + row] = (unsigned)(m >> 32);
        }
    }
}

// ---------------------------------------------------------------------------
// Kernel T: WT[n][k] = bf16(W[k][n])   (512x512)
// ---------------------------------------------------------------------------
__global__ __launch_bounds__(256) void transpose_w(const float* __restrict__ W,
                                                   unsigned short* __restrict__ WT) {
    __shared__ float tile[32][33];
    const int t = threadIdx.x;
    const int x = t & 31, y = t >> 5;
    const int tr = (blockIdx.x >> 4) * 32, tc = (blockIdx.x & 15) * 32;
#pragma unroll
    for (int i = 0; i < 4; i++) {
        int r = y + i * 8;
        tile[r][x] = W[(size_t)(tr + r) * DOUT + tc + x];
    }
    __syncthreads();
#pragma unroll
    for (int i = 0; i < 4; i++) {
        int r = y + i * 8;
        WT[(size_t)(tc + r) * DIN + tr + x] = f2bf(tile[x][r]);
    }
}

// ---------------------------------------------------------------------------
// Kernel A: Wh = h @ W (bf16 MFMA). 512 blocks x 16 rows, 4 waves (16r x 128c).
// Writes Wh in MFMA-B-FRAGMENT-TILED layout WhTt[tile_n][tile_k][q][l15][8]:
// tile = 16 cols x 32 k = 1024 B, so gat's B-frag load is ONE contiguous
// 1 KB wave-load (fixes the 16-way address divergence that was the wall).
// Also f1 = Wh@a1, f2 = Wh@a2, atomicMax of max(f2).
// ---------------------------------------------------------------------------
__global__ __launch_bounds__(256) void gemm_wh(
    const float* __restrict__ h, const unsigned short* __restrict__ WT,
    const float* __restrict__ a, unsigned short* __restrict__ WhTt,
    float* __restrict__ f1, float* __restrict__ f2, unsigned* __restrict__ Menc)
{
    __shared__ float f1s[4][16], f2s[4][16];
    const int t = threadIdx.x;
    const int w = t >> 6, lane = t & 63, l15 = lane & 15, q = lane >> 4;
    const int r0 = blockIdx.x * 16;
    const int wc0 = w * 128;

    floatx4 acc[8];
    const floatx4 z4 = {0.f, 0.f, 0.f, 0.f};
#pragma unroll
    for (int j = 0; j < 8; j++) acc[j] = z4;

    const float* hp = &h[(size_t)(r0 + l15) * DIN + q * 8];
    const unsigned short* bp = &WT[(size_t)(wc0 + l15) * DIN + q * 8];

    floatx4 hA[2][2];
    shortx8 bB[2][8];
    hA[0][0] = *(const floatx4*)hp;
    hA[0][1] = *(const floatx4*)(hp + 4);
#pragma unroll
    for (int nt = 0; nt < 8; nt++)
        bB[0][nt] = *(const shortx8*)(bp + (size_t)nt * 16 * DIN);

#pragma unroll 2
    for (int it = 0; it < 16; ++it) {
        const int c = it & 1, n = c ^ 1;
        const int kn = ((it + 1) & 15) * 32;
        hA[n][0] = *(const floatx4*)(hp + kn);
        hA[n][1] = *(const floatx4*)(hp + kn + 4);
#pragma unroll
        for (int nt = 0; nt < 8; nt++)
            bB[n][nt] = *(const shortx8*)(bp + (size_t)nt * 16 * DIN + kn);

        shortx8 af;
#pragma unroll
        for (int j = 0; j < 8; j++)
            af[j] = (short)f2bf(hA[c][j >> 2][j & 3]);
#pragma unroll
        for (int nt = 0; nt < 8; nt++)
            acc[nt] = __builtin_amdgcn_mfma_f32_16x16x32_bf16(af, bB[c][nt], acc[nt], 0, 0, 0);
    }

    // epilogue: tiled WhTt store (512-B contiguous per store inst) + f1/f2
    float a1v[8], a2v[8];
#pragma unroll
    for (int nt = 0; nt < 8; nt++) {
        int col = wc0 + nt * 16 + l15;
        a1v[nt] = a[col];
        a2v[nt] = a[DOUT + col];
    }
    {
        const int kk0 = r0 + q * 4;           // k-index of reg 0
        const int tile_k = kk0 >> 5;
        const int qq = (kk0 >> 3) & 3;
        const int j0 = kk0 & 7;               // 0 or 4
#pragma unroll
        for (int nt = 0; nt < 8; nt++) {
            const int tile_n = w * 8 + nt;
            ushortx4 pk;
#pragma unroll
            for (int reg = 0; reg < 4; reg++) pk[reg] = f2bf(acc[nt][reg]);
            *(ushortx4*)&WhTt[(((size_t)tile_n * 256 + tile_k) << 9) + qq * 128 + l15 * 8 + j0] = pk;
        }
    }
    float s1a[4], s2a[4];
#pragma unroll
    for (int reg = 0; reg < 4; reg++) {
        float s1 = 0.f, s2 = 0.f;
#pragma unroll
        for (int nt = 0; nt < 8; nt++) {
            s1 += acc[nt][reg] * a1v[nt];
            s2 += acc[nt][reg] * a2v[nt];
        }
        s1 += __shfl_xor(s1, 1, 64); s2 += __shfl_xor(s2, 1, 64);
        s1 += __shfl_xor(s1, 2, 64); s2 += __shfl_xor(s2, 2, 64);
        s1 += __shfl_xor(s1, 4, 64); s2 += __shfl_xor(s2, 4, 64);
        s1 += __shfl_xor(s1, 8, 64); s2 += __shfl_xor(s2, 8, 64);
        s1a[reg] = s1; s2a[reg] = s2;
    }
    if (l15 == 0) {
#pragma unroll
        for (int reg = 0; reg < 4; reg++) {
            f1s[w][q * 4 + reg] = s1a[reg];
            f2s[w][q * 4 + reg] = s2a[reg];
        }
    }
    __syncthreads();
    if (t < 16) {
        float v1 = f1s[0][t] + f1s[1][t] + f1s[2][t] + f1s[3][t];
        float v2 = f2s[0][t] + f2s[1][t] + f2s[2][t] + f2s[3][t];
        f1[r0 + t] = v1;
        f2[r0 + t] = v2;
        float mx = v2;
        mx = fmaxf(mx, __shfl_xor(mx, 1, 64));
        mx = fmaxf(mx, __shfl_xor(mx, 2, 64));
        mx = fmaxf(mx, __shfl_xor(mx, 4, 64));
        mx = fmaxf(mx, __shfl_xor(mx, 8, 64));
        if (t == 0) atomicMax(Menc, encf(mx));
    }
}

// ---------------------------------------------------------------------------
// Kernel 2: GAT aggregation partials. Grid = 1024 = 256 row-blocks x 4
// k-quarters (XCD-bound: kq=(b&7)>>1). Per iter per wave (32r x 128c x 32k):
//   B: 8 contiguous 1 KB wave-loads from tiled WhTt (was 128 transactions)
//   adj: 2 broadcast dword loads from bitmask (was 64 transactions)
//   f2: 2 small loads
// p built in registers in MFMA A-layout; bit-test masks. B double-buffer in
// HALVES (bA/bB, 32 VGPR) -> fits __launch_bounds__(256,3) = 3 waves/SIMD.
// Partials merged via atomicAdd (proven R4). m_i = lrelu(f1_i + max f2).
// ---------------------------------------------------------------------------
__global__ __launch_bounds__(256, 3) void gat_agg_part(
    const unsigned* __restrict__ bits, const unsigned short* __restrict__ WhTt,
    const float* __restrict__ f1, const float* __restrict__ f2,
    const unsigned* __restrict__ Menc, float* __restrict__ outacc,
    float* __restrict__ lsum)
{
    const int t = threadIdx.x;
    const int cw = t >> 6, lane = t & 63, l15 = lane & 15, q = lane >> 4;
    const int b = blockIdx.x;
    const int low3 = b & 7;
    const int kq = low3 >> 1;
    const int sub = low3 & 1;
    const int j8 = b >> 3;
    const int rb = (j8 + sub * 128 + kq * 64) & 255;
    const int r0 = rb * 32;
    const int kbase = kq * 64;                 // in k-tiles of 32

    const float M = decf(*Menc);
    const float f1v0 = f1[r0 + l15];
    const float f1v1 = f1[r0 + 16 + l15];
    const float mi0 = lrelu(f1v0 + M);
    const float mi1 = lrelu(f1v1 + M);

    floatx4 acc[2][8];
    const floatx4 z4 = {0.f, 0.f, 0.f, 0.f};
#pragma unroll
    for (int i = 0; i < 2; i++)
#pragma unroll
        for (int j = 0; j < 8; j++) acc[i][j] = z4;
    float ls0 = 0.f, ls1 = 0.f;

    // B base: tile_n = cw*8 + nt, tile_k = kbase + it; elem = (tile_n*256+tile_k)*512 + lane*8
    const unsigned short* bp = WhTt + (((size_t)(cw * 8) * 256 + kbase) << 9) + lane * 8;
    const unsigned* mb0 = bits + (size_t)kbase * NN + r0 + l15;
    const unsigned* mb1 = mb0 + 16;
    const float* fp = f2 + kq * 2048 + q * 8;

    unsigned mk0[2], mk1[2];
    floatx4  f2f[2][2];
    shortx8  bA[4], bB[4];

    mk0[0] = mb0[0];
    mk1[0] = mb1[0];
    f2f[0][0] = *(const floatx4*)fp;
    f2f[0][1] = *(const floatx4*)(fp + 4);
#pragma unroll
    for (int i = 0; i < 4; i++) {
        bA[i] = *(const shortx8*)(bp + ((size_t)i * 256 << 9));
        bB[i] = *(const shortx8*)(bp + ((size_t)(i + 4) * 256 << 9));
    }

#pragma unroll 2
    for (int it = 0; it < 64; ++it) {
        const int c = it & 1, n = c ^ 1;
        const int nx = (it + 1) & 63;          // wraps harmlessly on last iter

        // 1-deep prefetch of masks + f2
        mk0[n] = mb0[(size_t)nx * NN];
        mk1[n] = mb1[(size_t)nx * NN];
        f2f[n][0] = *(const floatx4*)(fp + nx * 32);
        f2f[n][1] = *(const floatx4*)(fp + nx * 32 + 4);

        // p fragments in MFMA A-layout (m=l15 / l15+16, k=q*8+j)
        const unsigned by0 = (mk0[c] >> (q * 8)) & 0xffu;
        const unsigned by1 = (mk1[c] >> (q * 8)) & 0xffu;
        unsigned pb0[8], pb1[8];
#pragma unroll
        for (int j = 0; j < 8; j++) {
            const float fj = f2f[c][j >> 2][j & 3];
            float p0 = __expf(lrelu(f1v0 + fj) - mi0);
            p0 = (by0 & (1u << j)) ? p0 : 0.f;
            ls0 += p0;
            pb0[j] = __float_as_uint(p0);
            float p1 = __expf(lrelu(f1v1 + fj) - mi1);
            p1 = (by1 & (1u << j)) ? p1 : 0.f;
            ls1 += p1;
            pb1[j] = __float_as_uint(p1);
        }
        union { unsigned u[4]; shortx8 v; } u0, u1;
#pragma unroll
        for (int j = 0; j < 4; j++) {
            u0.u[j] = __builtin_amdgcn_perm(pb0[2 * j + 1], pb0[2 * j], 0x07060302u);
            u1.u[j] = __builtin_amdgcn_perm(pb1[2 * j + 1], pb1[2 * j], 0x07060302u);
        }
        const shortx8 af0 = u0.v, af1 = u1.v;

        // half 1: MFMA with bA(it), then refill bA(it+1)
#pragma unroll
        for (int nt = 0; nt < 4; nt++) {
            acc[0][nt] = __builtin_amdgcn_mfma_f32_16x16x32_bf16(af0, bA[nt], acc[0][nt], 0, 0, 0);
            acc[1][nt] = __builtin_amdgcn_mfma_f32_16x16x32_bf16(af1, bA[nt], acc[1][nt], 0, 0, 0);
        }
#pragma unroll
        for (int i = 0; i < 4; i++)
            bA[i] = *(const shortx8*)(bp + (((size_t)i * 256 + nx) << 9));

        // half 2: MFMA with bB(it), then refill bB(it+1)
#pragma unroll
        for (int nt = 0; nt < 4; nt++) {
            acc[0][4 + nt] = __builtin_amdgcn_mfma_f32_16x16x32_bf16(af0, bB[nt], acc[0][4 + nt], 0, 0, 0);
            acc[1][4 + nt] = __builtin_amdgcn_mfma_f32_16x16x32_bf16(af1, bB[nt], acc[1][4 + nt], 0, 0, 0);
        }
#pragma unroll
        for (int i = 0; i < 4; i++)
            bB[i] = *(const shortx8*)(bp + (((size_t)(i + 4) * 256 + nx) << 9));
    }

    // row sums for this k-quarter
    ls0 += __shfl_xor(ls0, 16, 64); ls0 += __shfl_xor(ls0, 32, 64);
    ls1 += __shfl_xor(ls1, 16, 64); ls1 += __shfl_xor(ls1, 32, 64);
    if (cw == 0 && lane < 16) {
        atomicAdd(&lsum[r0 + lane], ls0);
        atomicAdd(&lsum[r0 + 16 + lane], ls1);
    }

    // merge partial O-tile (C-layout: row = mt*16 + q*4 + reg, col)
    const int wc0 = cw * 128;
#pragma unroll
    for (int mt = 0; mt < 2; mt++) {
#pragma unroll
        for (int nt = 0; nt < 8; nt++) {
            const int col = wc0 + nt * 16 + l15;
#pragma unroll
            for (int reg = 0; reg < 4; reg++) {
                const int row = mt * 16 + q * 4 + reg;
                atomicAdd(&outacc[(size_t)(r0 + row) * DOUT + col], acc[mt][nt][reg]);
            }
        }
    }
}

// ---------------------------------------------------------------------------
// Kernel 3: out = elu(acc / lsum), in place.
// ---------------------------------------------------------------------------
__global__ __launch_bounds__(256) void finalize(
    float* __restrict__ out, const float* __restrict__ lsum)
{
    const int t = threadIdx.x;
    const int row = blockIdx.x * 2 + (t >> 7);
    const int c4 = (t & 127) * 4;
    const float iv = 1.f / lsum[row];
    float* p = &out[(size_t)row * DOUT + c4];
    floatx4 v = *(const floatx4*)p;
    floatx4 o;
#pragma unroll
    for (int j = 0; j < 4; j++) {
        const float x = v[j] * iv;
        o[j] = (x > 0.f) ? x : (__expf(x) - 1.f);
    }
    *(floatx4*)p = o;
}

// ---------------------------------------------------------------------------
extern "C" void kernel_launch(void* const* d_in, const int* in_sizes, int n_in,
                              void* d_out, int out_size, void* d_ws, size_t ws_size,
                              hipStream_t stream) {
    const float* h   = (const float*)d_in[0];
    const int*   adj = (const int*)d_in[1];
    const float* W   = (const float*)d_in[2];
    const float* a   = (const float*)d_in[3];
    float* out = (float*)d_out;

    char* ws = (char*)d_ws;
    unsigned short* WT    = (unsigned short*)ws;                  // 512 KB
    unsigned short* WhTt  = (unsigned short*)(ws + 524288);       // 8 MB (tiled)
    unsigned*       bits  = (unsigned*)(ws + 8912896);            // 8 MB
    float*          f1    = (float*)(ws + 17301504);              // 32 KB
    float*          f2    = (float*)(ws + 17334272);              // 32 KB
    float*          lsum  = (float*)(ws + 17367040);              // 32 KB
    unsigned*       Menc  = (unsigned*)(ws + 17399808);           // 4 B

    hipMemsetAsync(out, 0, (size_t)NN * DOUT * sizeof(float), stream);
    hipMemsetAsync(lsum, 0, NN * sizeof(float), stream);
    hipMemsetAsync(Menc, 0, 4, stream);
    pack_adj<<<NN, 256, 0, stream>>>(adj, bits);
    transpose_w<<<256, 256, 0, stream>>>(W, WT);
    gemm_wh<<<512, 256, 0, stream>>>(h, WT, a, WhTt, f1, f2, Menc);
    gat_agg_part<<<1024, 256, 0, stream>>>(bits, WhTt, f1, f2, Menc, out, lsum);
    finalize<<<4096, 256, 0, stream>>>(out, lsum);
}

// Round 10
// 647.842 us; speedup vs baseline: 1.3438x; 1.1091x over previous
//
#include <hip/hip_runtime.h>
#include <stdint.h>

#define NN   8192
#define DIN  512
#define DOUT 512
#define ALPHA 0.2f

typedef float          floatx4  __attribute__((ext_vector_type(4)));
typedef short          shortx8  __attribute__((ext_vector_type(8)));
typedef unsigned short ushortx4 __attribute__((ext_vector_type(4)));
typedef int            intx4    __attribute__((ext_vector_type(4)));

__device__ inline unsigned short f2bf(float x) {
    union { float f; unsigned u; } v; v.f = x;
    return (unsigned short)((v.u + 0x7FFFu + ((v.u >> 16) & 1u)) >> 16);
}
__device__ inline unsigned encf(float x) {
    union { float f; unsigned u; } v; v.f = x;
    return (v.u & 0x80000000u) ? ~v.u : (v.u | 0x80000000u);
}
__device__ inline float decf(unsigned e) {
    union { float f; unsigned u; } v;
    v.u = (e & 0x80000000u) ? (e & 0x7FFFFFFFu) : ~e;
    return v.f;
}
__device__ inline float lrelu(float x) { return fmaxf(x, ALPHA * x); }

// ---------------------------------------------------------------------------
// Kernel P: pack adj into bitmask, k-transposed: bits[kt][row], kt = k>>5.
// ---------------------------------------------------------------------------
__global__ __launch_bounds__(256) void pack_adj(const int* __restrict__ adj,
                                                unsigned* __restrict__ bits) {
    const int row = blockIdx.x;
    const int t = threadIdx.x;
    const int w = t >> 6, lane = t & 63;
    const int* rp = adj + (size_t)row * NN;
#pragma unroll 4
    for (int it = 0; it < 32; ++it) {
        const int col = it * 256 + w * 64 + lane;
        const int v = __builtin_nontemporal_load(rp + col);
        const unsigned long long m = __ballot(v > 0);
        if (lane == 0) {
            const int kt = it * 8 + w * 2;
            bits[(size_t)kt * NN + row] = (unsigned)m;
            bits[(size_t)(kt + 1) * NN + row] = (unsigned)(m >> 32);
        }
    }
}

// ---------------------------------------------------------------------------
// Kernel T: WT[n][k] = bf16(W[k][n])   (512x512)
// ---------------------------------------------------------------------------
__global__ __launch_bounds__(256) void transpose_w(const float* __restrict__ W,
                                                   unsigned short* __restrict__ WT) {
    __shared__ float tile[32][33];
    const int t = threadIdx.x;
    const int x = t & 31, y = t >> 5;
    const int tr = (blockIdx.x >> 4) * 32, tc = (blockIdx.x & 15) * 32;
#pragma unroll
    for (int i = 0; i < 4; i++) {
        int r = y + i * 8;
        tile[r][x] = W[(size_t)(tr + r) * DOUT + tc + x];
    }
    __syncthreads();
#pragma unroll
    for (int i = 0; i < 4; i++) {
        int r = y + i * 8;
        WT[(size_t)(tc + r) * DIN + tr + x] = f2bf(tile[x][r]);
    }
}

// ---------------------------------------------------------------------------
// Kernel A: Wh = h @ W (bf16 MFMA). 512 blocks x 16 rows, 4 waves (16r x 128c).
// Writes Wh in MFMA-B-fragment-tiled layout WhTt[tile_n][tile_k][q][l15][8]
// (tile = 16 cols x 32 k = 1 KB contiguous), f1 = Wh@a1, f2 = Wh@a2, max(f2).
// ---------------------------------------------------------------------------
__global__ __launch_bounds__(256) void gemm_wh(
    const float* __restrict__ h, const unsigned short* __restrict__ WT,
    const float* __restrict__ a, unsigned short* __restrict__ WhTt,
    float* __restrict__ f1, float* __restrict__ f2, unsigned* __restrict__ Menc)
{
    __shared__ float f1s[4][16], f2s[4][16];
    const int t = threadIdx.x;
    const int w = t >> 6, lane = t & 63, l15 = lane & 15, q = lane >> 4;
    const int r0 = blockIdx.x * 16;
    const int wc0 = w * 128;

    floatx4 acc[8];
    const floatx4 z4 = {0.f, 0.f, 0.f, 0.f};
#pragma unroll
    for (int j = 0; j < 8; j++) acc[j] = z4;

    const float* hp = &h[(size_t)(r0 + l15) * DIN + q * 8];
    const unsigned short* bp = &WT[(size_t)(wc0 + l15) * DIN + q * 8];

    floatx4 hA[2][2];
    shortx8 bB[2][8];
    hA[0][0] = *(const floatx4*)hp;
    hA[0][1] = *(const floatx4*)(hp + 4);
#pragma unroll
    for (int nt = 0; nt < 8; nt++)
        bB[0][nt] = *(const shortx8*)(bp + (size_t)nt * 16 * DIN);

#pragma unroll 2
    for (int it = 0; it < 16; ++it) {
        const int c = it & 1, n = c ^ 1;
        const int kn = ((it + 1) & 15) * 32;
        hA[n][0] = *(const floatx4*)(hp + kn);
        hA[n][1] = *(const floatx4*)(hp + kn + 4);
#pragma unroll
        for (int nt = 0; nt < 8; nt++)
            bB[n][nt] = *(const shortx8*)(bp + (size_t)nt * 16 * DIN + kn);

        shortx8 af;
#pragma unroll
        for (int j = 0; j < 8; j++)
            af[j] = (short)f2bf(hA[c][j >> 2][j & 3]);
#pragma unroll
        for (int nt = 0; nt < 8; nt++)
            acc[nt] = __builtin_amdgcn_mfma_f32_16x16x32_bf16(af, bB[c][nt], acc[nt], 0, 0, 0);
    }

    // epilogue: tiled WhTt store + f1/f2 + max(f2)
    float a1v[8], a2v[8];
#pragma unroll
    for (int nt = 0; nt < 8; nt++) {
        int col = wc0 + nt * 16 + l15;
        a1v[nt] = a[col];
        a2v[nt] = a[DOUT + col];
    }
    {
        const int kk0 = r0 + q * 4;
        const int tile_k = kk0 >> 5;
        const int qq = (kk0 >> 3) & 3;
        const int j0 = kk0 & 7;
#pragma unroll
        for (int nt = 0; nt < 8; nt++) {
            const int tile_n = w * 8 + nt;
            ushortx4 pk;
#pragma unroll
            for (int reg = 0; reg < 4; reg++) pk[reg] = f2bf(acc[nt][reg]);
            *(ushortx4*)&WhTt[(((size_t)tile_n * 256 + tile_k) << 9) + qq * 128 + l15 * 8 + j0] = pk;
        }
    }
    float s1a[4], s2a[4];
#pragma unroll
    for (int reg = 0; reg < 4; reg++) {
        float s1 = 0.f, s2 = 0.f;
#pragma unroll
        for (int nt = 0; nt < 8; nt++) {
            s1 += acc[nt][reg] * a1v[nt];
            s2 += acc[nt][reg] * a2v[nt];
        }
        s1 += __shfl_xor(s1, 1, 64); s2 += __shfl_xor(s2, 1, 64);
        s1 += __shfl_xor(s1, 2, 64); s2 += __shfl_xor(s2, 2, 64);
        s1 += __shfl_xor(s1, 4, 64); s2 += __shfl_xor(s2, 4, 64);
        s1 += __shfl_xor(s1, 8, 64); s2 += __shfl_xor(s2, 8, 64);
        s1a[reg] = s1; s2a[reg] = s2;
    }
    if (l15 == 0) {
#pragma unroll
        for (int reg = 0; reg < 4; reg++) {
            f1s[w][q * 4 + reg] = s1a[reg];
            f2s[w][q * 4 + reg] = s2a[reg];
        }
    }
    __syncthreads();
    if (t < 16) {
        float v1 = f1s[0][t] + f1s[1][t] + f1s[2][t] + f1s[3][t];
        float v2 = f2s[0][t] + f2s[1][t] + f2s[2][t] + f2s[3][t];
        f1[r0 + t] = v1;
        f2[r0 + t] = v2;
        float mx = v2;
        mx = fmaxf(mx, __shfl_xor(mx, 1, 64));
        mx = fmaxf(mx, __shfl_xor(mx, 2, 64));
        mx = fmaxf(mx, __shfl_xor(mx, 4, 64));
        mx = fmaxf(mx, __shfl_xor(mx, 8, 64));
        if (t == 0) atomicMax(Menc, encf(mx));
    }
}

// ---------------------------------------------------------------------------
// Kernel 2: fused GAT aggregation, IN-BLOCK k-split. Grid = 1024 blocks
// (rb = b>>2 row-block of 32, bc = b&3 col-group of 128) = exactly 4/CU;
// __launch_bounds__(256,4) (VGPR 68 < 128 cap) -> ~50% occupancy, no tail.
// Wave = one k-quarter (kq = wave id), inner loop identical to R8 (proven):
//   B: 8 contiguous 1 KB wave-loads from tiled WhTt; masks: 2 broadcast
//   dwords from packed bits; p built in registers in MFMA A-layout.
// Merge once per kernel: 4 staged barriers into padded LDS (stride 132 ->
// 2-way bank aliasing = free), in-block row-sums, ELU + direct stores.
// NO atomics, NO out-memset, NO finalize kernel (R8's atomic epilogue gone).
// m_i = lrelu(f1_i + max f2) upper-bounds every masked score -> single pass.
// ---------------------------------------------------------------------------
__global__ __launch_bounds__(256, 4) void gat_agg(
    const unsigned* __restrict__ bits, const unsigned short* __restrict__ WhTt,
    const float* __restrict__ f1, const float* __restrict__ f2,
    const unsigned* __restrict__ Menc, float* __restrict__ out)
{
    __shared__ float red[32][132];
    __shared__ float lsums[4][32];
    __shared__ float linv[32];

    const int t = threadIdx.x;
    const int kq = t >> 6, lane = t & 63, l15 = lane & 15, q = lane >> 4;
    const int b = blockIdx.x;
    const int bc = b & 3;                      // col-group (128 cols)
    const int rb = b >> 2;                     // row-block (32 rows)
    const int r0 = rb * 32;
    const int kbase = kq * 64;                 // k-tiles of 32

    const float M = decf(*Menc);
    const float f1v0 = f1[r0 + l15];
    const float f1v1 = f1[r0 + 16 + l15];
    const float mi0 = lrelu(f1v0 + M);
    const float mi1 = lrelu(f1v1 + M);

    floatx4 acc[2][8];
    const floatx4 z4 = {0.f, 0.f, 0.f, 0.f};
#pragma unroll
    for (int i = 0; i < 2; i++)
#pragma unroll
        for (int j = 0; j < 8; j++) acc[i][j] = z4;
    float ls0 = 0.f, ls1 = 0.f;

    // B base: tile_n = bc*8 + nt, tile_k = kbase + it
    const unsigned short* bp = WhTt + (((size_t)(bc * 8) * 256 + kbase) << 9) + lane * 8;
    const unsigned* mb0 = bits + (size_t)kbase * NN + r0 + l15;
    const unsigned* mb1 = mb0 + 16;
    const float* fp = f2 + kq * 2048 + q * 8;

    unsigned mk0[2], mk1[2];
    floatx4  f2f[2][2];
    shortx8  bA[4], bB[4];

    mk0[0] = mb0[0];
    mk1[0] = mb1[0];
    f2f[0][0] = *(const floatx4*)fp;
    f2f[0][1] = *(const floatx4*)(fp + 4);
#pragma unroll
    for (int i = 0; i < 4; i++) {
        bA[i] = *(const shortx8*)(bp + ((size_t)i * 256 << 9));
        bB[i] = *(const shortx8*)(bp + ((size_t)(i + 4) * 256 << 9));
    }

#pragma unroll 2
    for (int it = 0; it < 64; ++it) {
        const int c = it & 1, n = c ^ 1;
        const int nx = (it + 1) & 63;          // wraps harmlessly on last iter

        mk0[n] = mb0[(size_t)nx * NN];
        mk1[n] = mb1[(size_t)nx * NN];
        f2f[n][0] = *(const floatx4*)(fp + nx * 32);
        f2f[n][1] = *(const floatx4*)(fp + nx * 32 + 4);

        const unsigned by0 = (mk0[c] >> (q * 8)) & 0xffu;
        const unsigned by1 = (mk1[c] >> (q * 8)) & 0xffu;
        unsigned pb0[8], pb1[8];
#pragma unroll
        for (int j = 0; j < 8; j++) {
            const float fj = f2f[c][j >> 2][j & 3];
            float p0 = __expf(lrelu(f1v0 + fj) - mi0);
            p0 = (by0 & (1u << j)) ? p0 : 0.f;
            ls0 += p0;
            pb0[j] = __float_as_uint(p0);
            float p1 = __expf(lrelu(f1v1 + fj) - mi1);
            p1 = (by1 & (1u << j)) ? p1 : 0.f;
            ls1 += p1;
            pb1[j] = __float_as_uint(p1);
        }
        union { unsigned u[4]; shortx8 v; } u0, u1;
#pragma unroll
        for (int j = 0; j < 4; j++) {
            u0.u[j] = __builtin_amdgcn_perm(pb0[2 * j + 1], pb0[2 * j], 0x07060302u);
            u1.u[j] = __builtin_amdgcn_perm(pb1[2 * j + 1], pb1[2 * j], 0x07060302u);
        }
        const shortx8 af0 = u0.v, af1 = u1.v;

#pragma unroll
        for (int nt = 0; nt < 4; nt++) {
            acc[0][nt] = __builtin_amdgcn_mfma_f32_16x16x32_bf16(af0, bA[nt], acc[0][nt], 0, 0, 0);
            acc[1][nt] = __builtin_amdgcn_mfma_f32_16x16x32_bf16(af1, bA[nt], acc[1][nt], 0, 0, 0);
        }
#pragma unroll
        for (int i = 0; i < 4; i++)
            bA[i] = *(const shortx8*)(bp + (((size_t)i * 256 + nx) << 9));

#pragma unroll
        for (int nt = 0; nt < 4; nt++) {
            acc[0][4 + nt] = __builtin_amdgcn_mfma_f32_16x16x32_bf16(af0, bB[nt], acc[0][4 + nt], 0, 0, 0);
            acc[1][4 + nt] = __builtin_amdgcn_mfma_f32_16x16x32_bf16(af1, bB[nt], acc[1][4 + nt], 0, 0, 0);
        }
#pragma unroll
        for (int i = 0; i < 4; i++)
            bB[i] = *(const shortx8*)(bp + (((size_t)(i + 4) * 256 + nx) << 9));
    }

    // per-quarter row sums (reduce over q-lanes) -> LDS
    ls0 += __shfl_xor(ls0, 16, 64); ls0 += __shfl_xor(ls0, 32, 64);
    ls1 += __shfl_xor(ls1, 16, 64); ls1 += __shfl_xor(ls1, 32, 64);
    if (lane < 16) {
        lsums[kq][lane] = ls0;
        lsums[kq][16 + lane] = ls1;
    }

    // staged k-quarter merge into LDS (C-layout: row = mt*16+q*4+reg)
#pragma unroll 1
    for (int g = 0; g < 4; ++g) {
        if (kq == g) {
#pragma unroll
            for (int mt = 0; mt < 2; mt++)
#pragma unroll
                for (int nt = 0; nt < 8; nt++) {
                    const int col = nt * 16 + l15;
#pragma unroll
                    for (int reg = 0; reg < 4; reg++) {
                        const int row = mt * 16 + q * 4 + reg;
                        if (g == 0) red[row][col] = acc[mt][nt][reg];
                        else        red[row][col] += acc[mt][nt][reg];
                    }
                }
        }
        __syncthreads();
    }
    if (t < 32)
        linv[t] = 1.f / (lsums[0][t] + lsums[1][t] + lsums[2][t] + lsums[3][t]);
    __syncthreads();

    // epilogue: normalize + ELU + coalesced float4 stores (no atomics)
#pragma unroll
    for (int j = 0; j < 4; ++j) {
        const int lin = j * 256 + t;
        const int row = lin >> 5;
        const int c4 = (lin & 31) * 4;
        const float iv = linv[row];
        const floatx4 v = *(const floatx4*)&red[row][c4];
        floatx4 o;
#pragma unroll
        for (int jj = 0; jj < 4; jj++) {
            const float x = v[jj] * iv;
            o[jj] = (x > 0.f) ? x : (__expf(x) - 1.f);
        }
        *(floatx4*)&out[(size_t)(r0 + row) * DOUT + bc * 128 + c4] = o;
    }
}

// ---------------------------------------------------------------------------
extern "C" void kernel_launch(void* const* d_in, const int* in_sizes, int n_in,
                              void* d_out, int out_size, void* d_ws, size_t ws_size,
                              hipStream_t stream) {
    const float* h   = (const float*)d_in[0];
    const int*   adj = (const int*)d_in[1];
    const float* W   = (const float*)d_in[2];
    const float* a   = (const float*)d_in[3];
    float* out = (float*)d_out;

    char* ws = (char*)d_ws;
    unsigned short* WT    = (unsigned short*)ws;                  // 512 KB
    unsigned short* WhTt  = (unsigned short*)(ws + 524288);       // 8 MB (tiled)
    unsigned*       bits  = (unsigned*)(ws + 8912896);            // 8 MB
    float*          f1    = (float*)(ws + 17301504);              // 32 KB
    float*          f2    = (float*)(ws + 17334272);              // 32 KB
    unsigned*       Menc  = (unsigned*)(ws + 17367040);           // 4 B

    hipMemsetAsync(Menc, 0, 4, stream);
    pack_adj<<<NN, 256, 0, stream>>>(adj, bits);
    transpose_w<<<256, 256, 0, stream>>>(W, WT);
    gemm_wh<<<512, 256, 0, stream>>>(h, WT, a, WhTt, f1, f2, Menc);
    gat_agg<<<1024, 256, 0, stream>>>(bits, WhTt, f1, f2, Menc, out);
}

// Round 11
// 531.294 us; speedup vs baseline: 1.6385x; 1.2194x over previous
//
#include <hip/hip_runtime.h>
#include <stdint.h>

#define NN   8192
#define DIN  512
#define DOUT 512
#define ALPHA 0.2f

typedef float          floatx4  __attribute__((ext_vector_type(4)));
typedef float          floatx2  __attribute__((ext_vector_type(2)));
typedef short          shortx8  __attribute__((ext_vector_type(8)));
typedef unsigned short ushortx4 __attribute__((ext_vector_type(4)));
typedef int            intx4    __attribute__((ext_vector_type(4)));

__device__ inline unsigned short f2bf(float x) {
    union { float f; unsigned u; } v; v.f = x;
    return (unsigned short)((v.u + 0x7FFFu + ((v.u >> 16) & 1u)) >> 16);
}
__device__ inline unsigned encf(float x) {
    union { float f; unsigned u; } v; v.f = x;
    return (v.u & 0x80000000u) ? ~v.u : (v.u | 0x80000000u);
}
__device__ inline float decf(unsigned e) {
    union { float f; unsigned u; } v;
    v.u = (e & 0x80000000u) ? (e & 0x7FFFFFFFu) : ~e;
    return v.f;
}
__device__ inline float lrelu(float x) { return fmaxf(x, ALPHA * x); }

// ---------------------------------------------------------------------------
// Kernel P: pack adj into bitmask, k-transposed: bits[kt][row], kt = k>>5.
// ---------------------------------------------------------------------------
__global__ __launch_bounds__(256) void pack_adj(const int* __restrict__ adj,
                                                unsigned* __restrict__ bits) {
    const int row = blockIdx.x;
    const int t = threadIdx.x;
    const int w = t >> 6, lane = t & 63;
    const int* rp = adj + (size_t)row * NN;
#pragma unroll 4
    for (int it = 0; it < 32; ++it) {
        const int col = it * 256 + w * 64 + lane;
        const int v = __builtin_nontemporal_load(rp + col);
        const unsigned long long m = __ballot(v > 0);
        if (lane == 0) {
            const int kt = it * 8 + w * 2;
            bits[(size_t)kt * NN + row] = (unsigned)m;
            bits[(size_t)(kt + 1) * NN + row] = (unsigned)(m >> 32);
        }
    }
}

// ---------------------------------------------------------------------------
// Kernel T: WT[n][k] = bf16(W[k][n])   (512x512)
// ---------------------------------------------------------------------------
__global__ __launch_bounds__(256) void transpose_w(const float* __restrict__ W,
                                                   unsigned short* __restrict__ WT) {
    __shared__ float tile[32][33];
    const int t = threadIdx.x;
    const int x = t & 31, y = t >> 5;
    const int tr = (blockIdx.x >> 4) * 32, tc = (blockIdx.x & 15) * 32;
#pragma unroll
    for (int i = 0; i < 4; i++) {
        int r = y + i * 8;
        tile[r][x] = W[(size_t)(tr + r) * DOUT + tc + x];
    }
    __syncthreads();
#pragma unroll
    for (int i = 0; i < 4; i++) {
        int r = y + i * 8;
        WT[(size_t)(tc + r) * DIN + tr + x] = f2bf(tile[x][r]);
    }
}

// ---------------------------------------------------------------------------
// Kernel A: Wh = h @ W (bf16 MFMA). 512 blocks x 16 rows, 4 waves (16r x 128c).
// Writes Wh in k-major fragment-tiled layout WhTt[tile_k][tile_n][512]
// (tile = 16 cols x 32 k = 1 KB contiguous; k-major so gat's 4 B-tiles per
// (iter,wave) are one 4 KB contiguous run), f1 = Wh@a1, f2 = Wh@a2, max(f2).
// ---------------------------------------------------------------------------
__global__ __launch_bounds__(256) void gemm_wh(
    const float* __restrict__ h, const unsigned short* __restrict__ WT,
    const float* __restrict__ a, unsigned short* __restrict__ WhTt,
    float* __restrict__ f1, float* __restrict__ f2, unsigned* __restrict__ Menc)
{
    __shared__ float f1s[4][16], f2s[4][16];
    const int t = threadIdx.x;
    const int w = t >> 6, lane = t & 63, l15 = lane & 15, q = lane >> 4;
    const int r0 = blockIdx.x * 16;
    const int wc0 = w * 128;

    floatx4 acc[8];
    const floatx4 z4 = {0.f, 0.f, 0.f, 0.f};
#pragma unroll
    for (int j = 0; j < 8; j++) acc[j] = z4;

    const float* hp = &h[(size_t)(r0 + l15) * DIN + q * 8];
    const unsigned short* bp = &WT[(size_t)(wc0 + l15) * DIN + q * 8];

    floatx4 hA[2][2];
    shortx8 bB[2][8];
    hA[0][0] = *(const floatx4*)hp;
    hA[0][1] = *(const floatx4*)(hp + 4);
#pragma unroll
    for (int nt = 0; nt < 8; nt++)
        bB[0][nt] = *(const shortx8*)(bp + (size_t)nt * 16 * DIN);

#pragma unroll 2
    for (int it = 0; it < 16; ++it) {
        const int c = it & 1, n = c ^ 1;
        const int kn = ((it + 1) & 15) * 32;
        hA[n][0] = *(const floatx4*)(hp + kn);
        hA[n][1] = *(const floatx4*)(hp + kn + 4);
#pragma unroll
        for (int nt = 0; nt < 8; nt++)
            bB[n][nt] = *(const shortx8*)(bp + (size_t)nt * 16 * DIN + kn);

        shortx8 af;
#pragma unroll
        for (int j = 0; j < 8; j++)
            af[j] = (short)f2bf(hA[c][j >> 2][j & 3]);
#pragma unroll
        for (int nt = 0; nt < 8; nt++)
            acc[nt] = __builtin_amdgcn_mfma_f32_16x16x32_bf16(af, bB[c][nt], acc[nt], 0, 0, 0);
    }

    // epilogue: tiled WhTt store (k-major) + f1/f2 + max(f2)
    float a1v[8], a2v[8];
#pragma unroll
    for (int nt = 0; nt < 8; nt++) {
        int col = wc0 + nt * 16 + l15;
        a1v[nt] = a[col];
        a2v[nt] = a[DOUT + col];
    }
    {
        const int kk0 = r0 + q * 4;
        const int tile_k = kk0 >> 5;
        const int qq = (kk0 >> 3) & 3;
        const int j0 = kk0 & 7;
#pragma unroll
        for (int nt = 0; nt < 8; nt++) {
            const int tile_n = w * 8 + nt;
            ushortx4 pk;
#pragma unroll
            for (int reg = 0; reg < 4; reg++) pk[reg] = f2bf(acc[nt][reg]);
            *(ushortx4*)&WhTt[(((size_t)tile_k * 32 + tile_n) << 9) + qq * 128 + l15 * 8 + j0] = pk;
        }
    }
    float s1a[4], s2a[4];
#pragma unroll
    for (int reg = 0; reg < 4; reg++) {
        float s1 = 0.f, s2 = 0.f;
#pragma unroll
        for (int nt = 0; nt < 8; nt++) {
            s1 += acc[nt][reg] * a1v[nt];
            s2 += acc[nt][reg] * a2v[nt];
        }
        s1 += __shfl_xor(s1, 1, 64); s2 += __shfl_xor(s2, 1, 64);
        s1 += __shfl_xor(s1, 2, 64); s2 += __shfl_xor(s2, 2, 64);
        s1 += __shfl_xor(s1, 4, 64); s2 += __shfl_xor(s2, 4, 64);
        s1 += __shfl_xor(s1, 8, 64); s2 += __shfl_xor(s2, 8, 64);
        s1a[reg] = s1; s2a[reg] = s2;
    }
    if (l15 == 0) {
#pragma unroll
        for (int reg = 0; reg < 4; reg++) {
            f1s[w][q * 4 + reg] = s1a[reg];
            f2s[w][q * 4 + reg] = s2a[reg];
        }
    }
    __syncthreads();
    if (t < 16) {
        float v1 = f1s[0][t] + f1s[1][t] + f1s[2][t] + f1s[3][t];
        float v2 = f2s[0][t] + f2s[1][t] + f2s[2][t] + f2s[3][t];
        f1[r0 + t] = v1;
        f2[r0 + t] = v2;
        float mx = v2;
        mx = fmaxf(mx, __shfl_xor(mx, 1, 64));
        mx = fmaxf(mx, __shfl_xor(mx, 2, 64));
        mx = fmaxf(mx, __shfl_xor(mx, 4, 64));
        mx = fmaxf(mx, __shfl_xor(mx, 8, 64));
        if (t == 0) atomicMax(Menc, encf(mx));
    }
}

// ---------------------------------------------------------------------------
// Kernel 2: GAT aggregation with SHARED p (exp computed ONCE per (row,k)).
// Grid = 256 blocks x 1024 threads (16 waves) = exactly 1 block/CU.
// Block = 32 rows x 512 cols x 8192 k. Wave = (ks = w>>3 k-half, cw = w&7
// col-group of 64); wave tile 32r x 64c x 4096k, 128 iters of 32k.
// Per iter: the 512 threads of a ks-group compute the 32x32 p tile (2 exps
// per thread, 67M exps total = minimum, vs 268M in R10), pack to bf16 and
// write a padded LDS tile (stride 40 elems -> conflict-free dword writes,
// 16B-aligned ds_read_b128 A-frags). B = 4 contiguous 1 KB loads from the
// k-major WhTt (1-deep reg double-buffer), all waves walk tile_k in the same
// global order -> chip-wide k-window stays hot in per-XCD L2. One barrier
// per iter (p double-buffered). k-halves merged IN-BLOCK via a 33 KB LDS
// stage (2 passes of 256 cols); lsums via LDS scatter; no atomics.
// m_i = lrelu(f1_i + max f2) upper-bounds every masked score -> single pass.
// ---------------------------------------------------------------------------
__global__ __launch_bounds__(1024, 4) void gat_agg(
    const unsigned* __restrict__ bits, const unsigned short* __restrict__ WhTt,
    const float* __restrict__ f1, const float* __restrict__ f2,
    const unsigned* __restrict__ Menc, float* __restrict__ out)
{
    __shared__ __align__(16) unsigned short pbuf[2][2][32 * 40]; // [ks][buf]
    __shared__ float red2[32][260];
    __shared__ float lsp[2][16][32];
    __shared__ float linv[32];

    const int t = threadIdx.x;
    const int w = t >> 6, lane = t & 63, l15 = lane & 15, q = lane >> 4;
    const int ks = w >> 3, cw = w & 7;
    const int u = cw * 64 + lane;             // 0..511 within ks-group
    const int prow = u & 31, pkc = u >> 5;    // p ownership: row, k-pair
    const int r0 = blockIdx.x * 32;

    const float M = decf(*Menc);
    const float f1v = f1[r0 + prow];
    const float mi = lrelu(f1v + M);

    floatx4 acc[2][4];
    const floatx4 z4 = {0.f, 0.f, 0.f, 0.f};
#pragma unroll
    for (int i = 0; i < 2; i++)
#pragma unroll
        for (int j = 0; j < 4; j++) acc[i][j] = z4;
    float ls = 0.f;

    // B base: tile_k = ks*128 + it, tile_n = cw*4 + nt (4 KB contiguous/iter)
    const unsigned short* bpp = WhTt + (((size_t)(ks * 128) * 32 + cw * 4) << 9) + lane * 8;
    const unsigned* mbp = bits + (size_t)(ks * 128) * NN + r0 + prow;
    const float* fpp = f2 + ks * 4096 + pkc * 2;

    unsigned mkr[2];
    floatx2  ffr[2];
    shortx8  breg[2][4];

    // prologue: p-inputs for it=0,1; p(0) -> pbuf[ks][0]; B(0)
    mkr[0] = mbp[0];
    mkr[1] = mbp[NN];
    ffr[0] = *(const floatx2*)fpp;
    ffr[1] = *(const floatx2*)(fpp + 32);
    {
        const unsigned mk = mkr[0];
        float e0 = lrelu(f1v + ffr[0][0]) - mi;
        float e1 = lrelu(f1v + ffr[0][1]) - mi;
        float p0 = __expf(e0), p1 = __expf(e1);
        p0 = (mk >> (pkc * 2)) & 1u ? p0 : 0.f;
        p1 = (mk >> (pkc * 2 + 1)) & 1u ? p1 : 0.f;
        ls += p0 + p1;
        unsigned d = __builtin_amdgcn_perm(__float_as_uint(p1), __float_as_uint(p0), 0x07060302u);
        *(unsigned*)&pbuf[ks][0][prow * 40 + pkc * 2] = d;
    }
#pragma unroll
    for (int nt = 0; nt < 4; nt++)
        breg[0][nt] = *(const shortx8*)(bpp + nt * 512);
    __syncthreads();

#pragma unroll 2
    for (int it = 0; it < 128; ++it) {
        const int c = it & 1, n = c ^ 1;
        const int nx = (it + 1) & 127;         // wraps harmlessly on last iters
        const int nx2 = (it + 2) & 127;

        // B(it+1) -> breg[n]
#pragma unroll
        for (int nt = 0; nt < 4; nt++)
            breg[n][nt] = *(const shortx8*)(bpp + (size_t)nx * 16384 + nt * 512);
        // p-inputs for it+2 -> slot c (p(it)'s inputs already consumed)
        const unsigned mk_n = mkr[n];
        const floatx2 ff_n = ffr[n];
        mkr[c] = mbp[(size_t)nx2 * NN];
        ffr[c] = *(const floatx2*)(fpp + nx2 * 32);

        // p(it+1) -> pbuf[ks][n]  (2 exps/thread, shared by 8 col-waves)
        {
            float e0 = lrelu(f1v + ff_n[0]) - mi;
            float e1 = lrelu(f1v + ff_n[1]) - mi;
            float p0 = __expf(e0), p1 = __expf(e1);
            p0 = (mk_n >> (pkc * 2)) & 1u ? p0 : 0.f;
            p1 = (mk_n >> (pkc * 2 + 1)) & 1u ? p1 : 0.f;
            ls += p0 + p1;
            unsigned d = __builtin_amdgcn_perm(__float_as_uint(p1), __float_as_uint(p0), 0x07060302u);
            *(unsigned*)&pbuf[ks][n][prow * 40 + pkc * 2] = d;
        }

        // A-frags from pbuf[ks][c] (p(it)); MFMA with breg[c]
        const shortx8 af0 = *(const shortx8*)&pbuf[ks][c][l15 * 40 + q * 8];
        const shortx8 af1 = *(const shortx8*)&pbuf[ks][c][(16 + l15) * 40 + q * 8];
#pragma unroll
        for (int nt = 0; nt < 4; nt++) {
            acc[0][nt] = __builtin_amdgcn_mfma_f32_16x16x32_bf16(af0, breg[c][nt], acc[0][nt], 0, 0, 0);
            acc[1][nt] = __builtin_amdgcn_mfma_f32_16x16x32_bf16(af1, breg[c][nt], acc[1][nt], 0, 0, 0);
        }
        __syncthreads();
    }
    // NOTE: p(128) computed on it=127 wraps to tile 0 -> garbage into the
    // unread buffer and a double-count of tile-0 p into ls? No: ls must not
    // double-count. Subtract the wrapped contribution computed at it=127:
    {
        // recompute tile-(ks*128 + 0)'s p contribution and subtract
        const unsigned mk = mbp[0];
        const floatx2 ff = *(const floatx2*)fpp;
        float e0 = lrelu(f1v + ff[0]) - mi;
        float e1 = lrelu(f1v + ff[1]) - mi;
        float p0 = __expf(e0), p1 = __expf(e1);
        p0 = (mk >> (pkc * 2)) & 1u ? p0 : 0.f;
        p1 = (mk >> (pkc * 2 + 1)) & 1u ? p1 : 0.f;
        ls -= p0 + p1;
    }

    // lsum merge: unique slot per thread, then 32 threads total them
    lsp[ks][pkc][prow] = ls;
    __syncthreads();
    if (t < 32) {
        float s = 0.f;
#pragma unroll
        for (int g = 0; g < 2; g++)
#pragma unroll
            for (int kc = 0; kc < 16; kc++) s += lsp[g][kc][t];
        linv[t] = 1.f / s;
    }
    __syncthreads();

    // in-block k-half merge + epilogue, 2 passes of 256 cols
#pragma unroll 1
    for (int half = 0; half < 2; ++half) {
        const int inHalf = (cw >> 2) == half;
        const int colb = (cw & 3) * 64;        // col base within half
        if (ks == 1 && inHalf) {
#pragma unroll
            for (int mt = 0; mt < 2; mt++)
#pragma unroll
                for (int nt = 0; nt < 4; nt++) {
                    const int col = colb + nt * 16 + l15;
#pragma unroll
                    for (int reg = 0; reg < 4; reg++)
                        red2[mt * 16 + q * 4 + reg][col] = acc[mt][nt][reg];
                }
        }
        __syncthreads();
        if (ks == 0 && inHalf) {
#pragma unroll
            for (int mt = 0; mt < 2; mt++)
#pragma unroll
                for (int nt = 0; nt < 4; nt++) {
                    const int col = colb + nt * 16 + l15;
#pragma unroll
                    for (int reg = 0; reg < 4; reg++) {
                        const int row = mt * 16 + q * 4 + reg;
                        float x = (acc[mt][nt][reg] + red2[row][col]) * linv[row];
                        x = (x > 0.f) ? x : (__expf(x) - 1.f);
                        out[(size_t)(r0 + row) * DOUT + half * 256 + col] = x;
                    }
                }
        }
        __syncthreads();
    }
}

// ---------------------------------------------------------------------------
extern "C" void kernel_launch(void* const* d_in, const int* in_sizes, int n_in,
                              void* d_out, int out_size, void* d_ws, size_t ws_size,
                              hipStream_t stream) {
    const float* h   = (const float*)d_in[0];
    const int*   adj = (const int*)d_in[1];
    const float* W   = (const float*)d_in[2];
    const float* a   = (const float*)d_in[3];
    float* out = (float*)d_out;

    char* ws = (char*)d_ws;
    unsigned short* WT    = (unsigned short*)ws;                  // 512 KB
    unsigned short* WhTt  = (unsigned short*)(ws + 524288);       // 8 MB (tiled)
    unsigned*       bits  = (unsigned*)(ws + 8912896);            // 8 MB
    float*          f1    = (float*)(ws + 17301504);              // 32 KB
    float*          f2    = (float*)(ws + 17334272);              // 32 KB
    unsigned*       Menc  = (unsigned*)(ws + 17367040);           // 4 B

    hipMemsetAsync(Menc, 0, 4, stream);
    pack_adj<<<NN, 256, 0, stream>>>(adj, bits);
    transpose_w<<<256, 256, 0, stream>>>(W, WT);
    gemm_wh<<<512, 256, 0, stream>>>(h, WT, a, WhTt, f1, f2, Menc);
    gat_agg<<<256, 1024, 0, stream>>>(bits, WhTt, f1, f2, Menc, out);
}

// Round 12
// 501.372 us; speedup vs baseline: 1.7363x; 1.0597x over previous
//
#include <hip/hip_runtime.h>
#include <stdint.h>

#define NN   8192
#define DIN  512
#define DOUT 512
#define ALPHA 0.2f

typedef float          floatx4  __attribute__((ext_vector_type(4)));
typedef float          floatx2  __attribute__((ext_vector_type(2)));
typedef short          shortx8  __attribute__((ext_vector_type(8)));
typedef unsigned short ushortx4 __attribute__((ext_vector_type(4)));
typedef int            intx2    __attribute__((ext_vector_type(2)));

__device__ inline unsigned short f2bf(float x) {
    union { float f; unsigned u; } v; v.f = x;
    return (unsigned short)((v.u + 0x7FFFu + ((v.u >> 16) & 1u)) >> 16);
}
__device__ inline unsigned encf(float x) {
    union { float f; unsigned u; } v; v.f = x;
    return (v.u & 0x80000000u) ? ~v.u : (v.u | 0x80000000u);
}
__device__ inline float decf(unsigned e) {
    union { float f; unsigned u; } v;
    v.u = (e & 0x80000000u) ? (e & 0x7FFFFFFFu) : ~e;
    return v.f;
}
__device__ inline float lrelu(float x) { return fmaxf(x, ALPHA * x); }

// ---------------------------------------------------------------------------
// Kernel T: WT[n][k] = bf16(W[k][n])   (512x512)
// ---------------------------------------------------------------------------
__global__ __launch_bounds__(256) void transpose_w(const float* __restrict__ W,
                                                   unsigned short* __restrict__ WT) {
    __shared__ float tile[32][33];
    const int t = threadIdx.x;
    const int x = t & 31, y = t >> 5;
    const int tr = (blockIdx.x >> 4) * 32, tc = (blockIdx.x & 15) * 32;
#pragma unroll
    for (int i = 0; i < 4; i++) {
        int r = y + i * 8;
        tile[r][x] = W[(size_t)(tr + r) * DOUT + tc + x];
    }
    __syncthreads();
#pragma unroll
    for (int i = 0; i < 4; i++) {
        int r = y + i * 8;
        WT[(size_t)(tc + r) * DIN + tr + x] = f2bf(tile[x][r]);
    }
}

// ---------------------------------------------------------------------------
// Kernel A: Wh = h @ W (bf16 MFMA). 512 blocks x 16 rows, 4 waves (16r x 128c).
// Writes Wh in k-major fragment-tiled layout WhTt[tile_k][tile_n][512]
// (tile = 16 cols x 32 k = 1 KB contiguous; k-major so gat's 4 B-tiles per
// (iter,wave) are one 4 KB contiguous run), f1 = Wh@a1, f2 = Wh@a2, max(f2).
// ---------------------------------------------------------------------------
__global__ __launch_bounds__(256) void gemm_wh(
    const float* __restrict__ h, const unsigned short* __restrict__ WT,
    const float* __restrict__ a, unsigned short* __restrict__ WhTt,
    float* __restrict__ f1, float* __restrict__ f2, unsigned* __restrict__ Menc)
{
    __shared__ float f1s[4][16], f2s[4][16];
    const int t = threadIdx.x;
    const int w = t >> 6, lane = t & 63, l15 = lane & 15, q = lane >> 4;
    const int r0 = blockIdx.x * 16;
    const int wc0 = w * 128;

    floatx4 acc[8];
    const floatx4 z4 = {0.f, 0.f, 0.f, 0.f};
#pragma unroll
    for (int j = 0; j < 8; j++) acc[j] = z4;

    const float* hp = &h[(size_t)(r0 + l15) * DIN + q * 8];
    const unsigned short* bp = &WT[(size_t)(wc0 + l15) * DIN + q * 8];

    floatx4 hA[2][2];
    shortx8 bB[2][8];
    hA[0][0] = *(const floatx4*)hp;
    hA[0][1] = *(const floatx4*)(hp + 4);
#pragma unroll
    for (int nt = 0; nt < 8; nt++)
        bB[0][nt] = *(const shortx8*)(bp + (size_t)nt * 16 * DIN);

#pragma unroll 2
    for (int it = 0; it < 16; ++it) {
        const int c = it & 1, n = c ^ 1;
        const int kn = ((it + 1) & 15) * 32;
        hA[n][0] = *(const floatx4*)(hp + kn);
        hA[n][1] = *(const floatx4*)(hp + kn + 4);
#pragma unroll
        for (int nt = 0; nt < 8; nt++)
            bB[n][nt] = *(const shortx8*)(bp + (size_t)nt * 16 * DIN + kn);

        shortx8 af;
#pragma unroll
        for (int j = 0; j < 8; j++)
            af[j] = (short)f2bf(hA[c][j >> 2][j & 3]);
#pragma unroll
        for (int nt = 0; nt < 8; nt++)
            acc[nt] = __builtin_amdgcn_mfma_f32_16x16x32_bf16(af, bB[c][nt], acc[nt], 0, 0, 0);
    }

    // epilogue: tiled WhTt store (k-major) + f1/f2 + max(f2)
    float a1v[8], a2v[8];
#pragma unroll
    for (int nt = 0; nt < 8; nt++) {
        int col = wc0 + nt * 16 + l15;
        a1v[nt] = a[col];
        a2v[nt] = a[DOUT + col];
    }
    {
        const int kk0 = r0 + q * 4;
        const int tile_k = kk0 >> 5;
        const int qq = (kk0 >> 3) & 3;
        const int j0 = kk0 & 7;
#pragma unroll
        for (int nt = 0; nt < 8; nt++) {
            const int tile_n = w * 8 + nt;
            ushortx4 pk;
#pragma unroll
            for (int reg = 0; reg < 4; reg++) pk[reg] = f2bf(acc[nt][reg]);
            *(ushortx4*)&WhTt[(((size_t)tile_k * 32 + tile_n) << 9) + qq * 128 + l15 * 8 + j0] = pk;
        }
    }
    float s1a[4], s2a[4];
#pragma unroll
    for (int reg = 0; reg < 4; reg++) {
        float s1 = 0.f, s2 = 0.f;
#pragma unroll
        for (int nt = 0; nt < 8; nt++) {
            s1 += acc[nt][reg] * a1v[nt];
            s2 += acc[nt][reg] * a2v[nt];
        }
        s1 += __shfl_xor(s1, 1, 64); s2 += __shfl_xor(s2, 1, 64);
        s1 += __shfl_xor(s1, 2, 64); s2 += __shfl_xor(s2, 2, 64);
        s1 += __shfl_xor(s1, 4, 64); s2 += __shfl_xor(s2, 4, 64);
        s1 += __shfl_xor(s1, 8, 64); s2 += __shfl_xor(s2, 8, 64);
        s1a[reg] = s1; s2a[reg] = s2;
    }
    if (l15 == 0) {
#pragma unroll
        for (int reg = 0; reg < 4; reg++) {
            f1s[w][q * 4 + reg] = s1a[reg];
            f2s[w][q * 4 + reg] = s2a[reg];
        }
    }
    __syncthreads();
    if (t < 16) {
        float v1 = f1s[0][t] + f1s[1][t] + f1s[2][t] + f1s[3][t];
        float v2 = f2s[0][t] + f2s[1][t] + f2s[2][t] + f2s[3][t];
        f1[r0 + t] = v1;
        f2[r0 + t] = v2;
        float mx = v2;
        mx = fmaxf(mx, __shfl_xor(mx, 1, 64));
        mx = fmaxf(mx, __shfl_xor(mx, 2, 64));
        mx = fmaxf(mx, __shfl_xor(mx, 4, 64));
        mx = fmaxf(mx, __shfl_xor(mx, 8, 64));
        if (t == 0) atomicMax(Menc, encf(mx));
    }
}

// ---------------------------------------------------------------------------
// Kernel 2: GAT aggregation, shared-p + FUSED adj read (pack_adj deleted).
// Grid = 256 blocks x 1024 threads = 1 block/CU. Block = 32r x 512c x 8192k.
// Wave = (ks = w>>3 k-half, cw = w&7 col-group of 64); 128 iters of 32k.
// p ownership prow = u>>4, pkc = u&15: 16 consecutive lanes share a row and
// read its 128 B adj slice contiguously (4 transactions/wave-load — avoids
// the R6 divergence wall), NONTEMPORAL so the 268 MB stream (43 us HBM,
// overlapped with L2/MFMA work) doesn't evict WhTt from L2. 2 exps per
// thread per iter (67M total = minimum), bf16-packed into double-buffered
// padded LDS (stride 40 -> conflict-free), one barrier/iter. B = 4
// contiguous 1 KB loads/iter from k-major WhTt, reg double-buffered; all
// waves walk tile_k in the same order -> k-window hot in L2. k-halves merged
// in-block via 33 KB LDS stage; no atomics, no extra kernels.
// m_i = lrelu(f1_i + max f2) upper-bounds every masked score -> single pass.
// ---------------------------------------------------------------------------
__global__ __launch_bounds__(1024, 4) void gat_agg(
    const int* __restrict__ adj, const unsigned short* __restrict__ WhTt,
    const float* __restrict__ f1, const float* __restrict__ f2,
    const unsigned* __restrict__ Menc, float* __restrict__ out)
{
    __shared__ __align__(16) unsigned short pbuf[2][2][32 * 40]; // [ks][buf]
    __shared__ float red2[32][260];
    __shared__ float lsp[2][16][32];
    __shared__ float linv[32];

    const int t = threadIdx.x;
    const int w = t >> 6, lane = t & 63, l15 = lane & 15, q = lane >> 4;
    const int ks = w >> 3, cw = w & 7;
    const int u = cw * 64 + lane;             // 0..511 within ks-group
    const int prow = u >> 4, pkc = u & 15;    // p ownership: row, k-pair
    const int r0 = blockIdx.x * 32;

    const float M = decf(*Menc);
    const float f1v = f1[r0 + prow];
    const float mi = lrelu(f1v + M);

    floatx4 acc[2][4];
    const floatx4 z4 = {0.f, 0.f, 0.f, 0.f};
#pragma unroll
    for (int i = 0; i < 2; i++)
#pragma unroll
        for (int j = 0; j < 4; j++) acc[i][j] = z4;
    float ls = 0.f;

    // B base: tile_k = ks*128 + it, tile_n = cw*4 + nt (4 KB contiguous/iter)
    const unsigned short* bpp = WhTt + (((size_t)(ks * 128) * 32 + cw * 4) << 9) + lane * 8;
    const int* arp = adj + (size_t)(r0 + prow) * NN + ks * 4096 + pkc * 2;
    const float* fpp = f2 + ks * 4096 + pkc * 2;

    intx2    adjr[2];
    floatx2  ffr[2];
    shortx8  breg[2][4];

    // prologue: inputs for tiles 0,1; p(0) -> pbuf[ks][0]; B(0)
    adjr[0] = __builtin_nontemporal_load((const intx2*)arp);
    adjr[1] = __builtin_nontemporal_load((const intx2*)(arp + 32));
    ffr[0] = *(const floatx2*)fpp;
    ffr[1] = *(const floatx2*)(fpp + 32);
    {
        float p0 = __expf(lrelu(f1v + ffr[0][0]) - mi);
        float p1 = __expf(lrelu(f1v + ffr[0][1]) - mi);
        p0 = (adjr[0][0] > 0) ? p0 : 0.f;
        p1 = (adjr[0][1] > 0) ? p1 : 0.f;
        ls += p0 + p1;
        unsigned d = __builtin_amdgcn_perm(__float_as_uint(p1), __float_as_uint(p0), 0x07060302u);
        *(unsigned*)&pbuf[ks][0][prow * 40 + pkc * 2] = d;
    }
#pragma unroll
    for (int nt = 0; nt < 4; nt++)
        breg[0][nt] = *(const shortx8*)(bpp + nt * 512);
    __syncthreads();

#pragma unroll 2
    for (int it = 0; it < 128; ++it) {
        const int c = it & 1, n = c ^ 1;
        const int nx = (it + 1) & 127;         // wraps harmlessly on last iter
        const int nx2 = (it + 2) & 127;

        // B(it+1) -> breg[n]
#pragma unroll
        for (int nt = 0; nt < 4; nt++)
            breg[n][nt] = *(const shortx8*)(bpp + (size_t)nx * 16384 + nt * 512);
        // inputs for it+2 -> slot c (slot c's tile-it inputs already consumed)
        const intx2   ad_n = adjr[n];
        const floatx2 ff_n = ffr[n];
        adjr[c] = __builtin_nontemporal_load((const intx2*)(arp + nx2 * 32));
        ffr[c] = *(const floatx2*)(fpp + nx2 * 32);

        // p(it+1) -> pbuf[ks][n]  (skip wrapped p(128) at it=127)
        if (it < 127) {
            float p0 = __expf(lrelu(f1v + ff_n[0]) - mi);
            float p1 = __expf(lrelu(f1v + ff_n[1]) - mi);
            p0 = (ad_n[0] > 0) ? p0 : 0.f;
            p1 = (ad_n[1] > 0) ? p1 : 0.f;
            ls += p0 + p1;
            unsigned d = __builtin_amdgcn_perm(__float_as_uint(p1), __float_as_uint(p0), 0x07060302u);
            *(unsigned*)&pbuf[ks][n][prow * 40 + pkc * 2] = d;
        }

        // A-frags from pbuf[ks][c] (p(it)); MFMA with breg[c]
        const shortx8 af0 = *(const shortx8*)&pbuf[ks][c][l15 * 40 + q * 8];
        const shortx8 af1 = *(const shortx8*)&pbuf[ks][c][(16 + l15) * 40 + q * 8];
#pragma unroll
        for (int nt = 0; nt < 4; nt++) {
            acc[0][nt] = __builtin_amdgcn_mfma_f32_16x16x32_bf16(af0, breg[c][nt], acc[0][nt], 0, 0, 0);
            acc[1][nt] = __builtin_amdgcn_mfma_f32_16x16x32_bf16(af1, breg[c][nt], acc[1][nt], 0, 0, 0);
        }
        __syncthreads();
    }

    // lsum merge: unique slot per thread, then 32 threads total them
    lsp[ks][pkc][prow] = ls;
    __syncthreads();
    if (t < 32) {
        float s = 0.f;
#pragma unroll
        for (int g = 0; g < 2; g++)
#pragma unroll
            for (int kc = 0; kc < 16; kc++) s += lsp[g][kc][t];
        linv[t] = 1.f / s;
    }
    __syncthreads();

    // in-block k-half merge + epilogue, 2 passes of 256 cols
#pragma unroll 1
    for (int half = 0; half < 2; ++half) {
        const int inHalf = (cw >> 2) == half;
        const int colb = (cw & 3) * 64;        // col base within half
        if (ks == 1 && inHalf) {
#pragma unroll
            for (int mt = 0; mt < 2; mt++)
#pragma unroll
                for (int nt = 0; nt < 4; nt++) {
                    const int col = colb + nt * 16 + l15;
#pragma unroll
                    for (int reg = 0; reg < 4; reg++)
                        red2[mt * 16 + q * 4 + reg][col] = acc[mt][nt][reg];
                }
        }
        __syncthreads();
        if (ks == 0 && inHalf) {
#pragma unroll
            for (int mt = 0; mt < 2; mt++)
#pragma unroll
                for (int nt = 0; nt < 4; nt++) {
                    const int col = colb + nt * 16 + l15;
#pragma unroll
                    for (int reg = 0; reg < 4; reg++) {
                        const int row = mt * 16 + q * 4 + reg;
                        float x = (acc[mt][nt][reg] + red2[row][col]) * linv[row];
                        x = (x > 0.f) ? x : (__expf(x) - 1.f);
                        out[(size_t)(r0 + row) * DOUT + half * 256 + col] = x;
                    }
                }
        }
        __syncthreads();
    }
}

// ---------------------------------------------------------------------------
extern "C" void kernel_launch(void* const* d_in, const int* in_sizes, int n_in,
                              void* d_out, int out_size, void* d_ws, size_t ws_size,
                              hipStream_t stream) {
    const float* h   = (const float*)d_in[0];
    const int*   adj = (const int*)d_in[1];
    const float* W   = (const float*)d_in[2];
    const float* a   = (const float*)d_in[3];
    float* out = (float*)d_out;

    char* ws = (char*)d_ws;
    unsigned short* WT    = (unsigned short*)ws;                  // 512 KB
    unsigned short* WhTt  = (unsigned short*)(ws + 524288);       // 8 MB (tiled)
    float*          f1    = (float*)(ws + 8912896);               // 32 KB
    float*          f2    = (float*)(ws + 8945664);               // 32 KB
    unsigned*       Menc  = (unsigned*)(ws + 8978432);            // 4 B

    hipMemsetAsync(Menc, 0, 4, stream);
    transpose_w<<<256, 256, 0, stream>>>(W, WT);
    gemm_wh<<<512, 256, 0, stream>>>(h, WT, a, WhTt, f1, f2, Menc);
    gat_agg<<<256, 1024, 0, stream>>>(adj, WhTt, f1, f2, Menc, out);
}